// Round 15
// baseline (124.471 us; speedup 1.0000x reference)
//
#include <hip/hip_runtime.h>
#include <hip/hip_bf16.h>
#include <math.h>

#define BATCH 128
#define WIN   128      // time steps / conv groups
#define NF    128      // conv spatial length
#define KC    16
#define POOL  65
#define NFC1  32       // number of LSTMs
#define HS    32       // hidden size
#define LW    40       // k2 h-buffer row stride (bf16 elems, 80B)
#define KP    1056     // fc1 K padded to multiple of 32
#define PSTR  1064     // poolb row stride (bf16 elems; 2128B -> conflict-free b128 reads)
#define RING  16       // h0 ring depth
#define GRP   4        // steps per flag-sync group

typedef float f32x4 __attribute__((ext_vector_type(4)));
typedef short bf16x8 __attribute__((ext_vector_type(8)));

#define LOG2E   1.442695041f
#define LOG2E2  2.885390082f

// gates arrive PRESCALED: i,f,o by -log2e ; g by +2*log2e (folded into weights).
// r6 form: sf = rcp(1+ef) keeps the recurrent c-chain short.
// 5 exp2 + 3 rcp + 1 med3; NaN-safe via c clamp.
__device__ __forceinline__ float cellf(float& c, float gi, float gf, float gg, float go) {
    float ei = __builtin_amdgcn_exp2f(gi);
    float ef = __builtin_amdgcn_exp2f(gf);
    float eg = __builtin_amdgcn_exp2f(gg);
    float eo = __builtin_amdgcn_exp2f(go);
    float sf = __builtin_amdgcn_rcpf(1.f + ef);
    c = fmaf(sf, c, (eg - 1.f) * __builtin_amdgcn_rcpf((1.f + ei) * (eg + 1.f)));
    float ec = __builtin_amdgcn_exp2f(__builtin_amdgcn_fmed3f(c, -30.f, 30.f) * LOG2E2);
    return (ec - 1.f) * __builtin_amdgcn_rcpf((1.f + eo) * (ec + 1.f));
}
__device__ __forceinline__ unsigned short f2bf(float x) {
    __hip_bfloat16 h = __float2bfloat16(x);
    unsigned short u; __builtin_memcpy(&u, &h, 2); return u;
}
__device__ __forceinline__ float bf2f(unsigned short u) {
    unsigned int v = ((unsigned int)u) << 16;
    float f; __builtin_memcpy(&f, &v, 4); return f;
}
__device__ __forceinline__ bf16x8 load_row8_scaled(const float* row, float sc) {
    float4 lo = ((const float4*)row)[0];
    float4 hi = ((const float4*)row)[1];
    union { bf16x8 v; unsigned short u[8]; } t;
    t.u[0] = f2bf(lo.x * sc); t.u[1] = f2bf(lo.y * sc); t.u[2] = f2bf(lo.z * sc); t.u[3] = f2bf(lo.w * sc);
    t.u[4] = f2bf(hi.x * sc); t.u[5] = f2bf(hi.y * sc); t.u[6] = f2bf(hi.z * sc); t.u[7] = f2bf(hi.w * sc);
    return t.v;
}

// ---------------- K0: convert fc1_w -> bf16, K-padded [32][KP] ----------------
__global__ __launch_bounds__(256) void k0_wconv(
    const float* __restrict__ fc1_w, unsigned short* __restrict__ w_bf)
{
    const int o = blockIdx.x;
    for (int i = threadIdx.x; i < KP; i += 256) {
        float v = (i < KC * POOL) ? fc1_w[(size_t)o * (KC * POOL) + i] : 0.f;
        w_bf[(size_t)o * KP + i] = f2bf(v);
    }
}

// ---------------- K1: grouped conv1d + relu + maxpool + fc1 (MFMA) ----------------
// grid = 128 w * 8 batch-tiles(16) = 1024 blocks of 256 threads (4 waves)
// -> 4 blocks/CU, 4 waves/SIMD (conv phase is latency-bound: more TLP).
__global__ __launch_bounds__(256, 4) void k1_conv_fc1(
    const float* __restrict__ x, const float* __restrict__ conv_w, const float* __restrict__ conv_b,
    const unsigned short* __restrict__ w_bf, const float* __restrict__ fc1_b, float* __restrict__ z)
{
    __shared__ __align__(16) unsigned short xp[16][132];     // bf16, xp[b][i] = x[i-1], 0-padded
    __shared__ __align__(16) unsigned short poolb[16 * PSTR];
    __shared__ float cw[KC][3];
    __shared__ float cb[KC];
    __shared__ float fb[NFC1];

    const int w = blockIdx.x >> 3;
    const int bbase = (blockIdx.x & 7) * 16;
    const int tid = threadIdx.x;

    if (tid < KC * 3) cw[tid / 3][tid % 3] = conv_w[(w * KC + tid / 3) * 3 + tid % 3];
    if (tid >= 64 && tid < 64 + KC) cb[tid - 64] = conv_b[w * KC + (tid - 64)];
    if (tid >= 96 && tid < 96 + NFC1) fb[tid - 96] = fc1_b[tid - 96];

    // vectorized x staging: 16 rows x 32 float4
    for (int i = tid; i < 16 * 32; i += 256) {
        int b = i >> 5, q = i & 31;
        float4 v = ((const float4*)(x + (size_t)(bbase + b) * (WIN * NF) + (size_t)w * NF))[q];
        unsigned short* dst = &xp[b][1 + q * 4];
        dst[0] = f2bf(v.x); dst[1] = f2bf(v.y); dst[2] = f2bf(v.z); dst[3] = f2bf(v.w);
    }
    if (tid < 16) { xp[tid][0] = 0; xp[tid][129] = 0; xp[tid][130] = 0; xp[tid][131] = 0; }
    __syncthreads();

    // conv + relu + pool: thread -> (b = tid>>4, k = tid&15); sliding window over xp
    {
        const int b = tid >> 4;        // 0..15
        const int k = tid & 15;
        const float w0 = cw[k][0], w1 = cw[k][1], w2 = cw[k][2], bb = cb[k];
        float v1 = 0.f;
        float v2 = bf2f(xp[b][0]);
        float v3 = bf2f(xp[b][1]);
        unsigned short* prow = &poolb[b * PSTR + k * POOL];
        #pragma unroll 5
        for (int j = 0; j < POOL; ++j) {
            float v0 = v1; v1 = v2; v2 = v3;
            v3 = bf2f(xp[b][2 * j + 2]);
            float oa = bb + w0 * v0 + w1 * v1 + w2 * v2;   // out(2j-1)
            float ob = bb + w0 * v1 + w1 * v2 + w2 * v3;   // out(2j)
            float m = 0.f;                                  // relu floor
            if (j > 0)        m = fmaxf(m, oa);
            if (j < POOL - 1) m = fmaxf(m, ob);
            prow[j] = f2bf(m);
        }
    }
    // zero K-pad tail (cols 1040..1055)
    for (int i = tid; i < 16 * (KP - KC * POOL); i += 256) {
        int b = i >> 4, c = i & 15;
        poolb[b * PSTR + KC * POOL + c] = 0;
    }
    __syncthreads();

    // fc1 MFMA: waves 0,1 -> o-tiles; waves 2,3 idle (phase is short)
    const int lane = tid & 63;
    const int wid = tid >> 6;
    if (wid < 2) {
        const int col = lane & 15;
        const int kg = lane >> 4;
        const int g = wid * 16 + col;
        f32x4 acc;
        {
            float bias = fb[g];
            acc[0] = bias; acc[1] = bias; acc[2] = bias; acc[3] = bias;
        }
        const unsigned short* wrow = w_bf + (size_t)g * KP;
        #pragma unroll 4
        for (int ks = 0; ks < KP / 32; ++ks) {
            bf16x8 aP = *(const bf16x8*)&poolb[col * PSTR + ks * 32 + kg * 8];
            bf16x8 bW = *(const bf16x8*)&wrow[ks * 32 + kg * 8];
            acc = __builtin_amdgcn_mfma_f32_16x16x32_bf16(aP, bW, acc, 0, 0, 0);
        }
        float4 st; st.x = acc[0]; st.y = acc[1]; st.z = acc[2]; st.w = acc[3];
        *(float4*)&z[(size_t)w * (NFC1 * BATCH) + (size_t)g * BATCH + bbase + kg * 4] = st;
    }
}

// ---------------- K2: 2-layer LSTM, one wave per LAYER, barrier-free ----------------
// grid = 256 blocks of 128 threads (2 waves) -> 1 block/CU.
// wave 0 = layer0 (all 8 gate n-tiles, 8 MFMA + 8 cells/lane)
// wave 1 = layer1 (16 MFMA + 8 cells/lane), chasing with lag >= GRP.
// Each layer's OWN recurrence is intra-wave (LDS ops of one wave complete in
// order) -> no barrier, no flag. Only the L0->L1 handoff syncs: depth-16 h0
// ring + ONE flag check per GRP=4 steps (r12/r14 failed on PER-STEP polling).
// Deadlock-free: L0 leads; L0's backpressure check (flg1 >= T-13) only binds
// if L0 is >13 steps ahead.
__global__ __launch_bounds__(128, 1) void k2_lstm_mfma(
    const float* __restrict__ w_ih0, const float* __restrict__ w_ih1,
    const float* __restrict__ w_hh, const float* __restrict__ b_lstm,
    const float* __restrict__ z, float* __restrict__ h1fin)
{
    __shared__ float zs[WIN][16];
    __shared__ __align__(16) unsigned short h0r_[RING][16 * LW];
    __shared__ __align__(16) unsigned short h1p_[2][16 * LW];
    __shared__ __align__(16) int flg[2];   // 0: L0 progress, 1: L1 progress

    const int f = blockIdx.x >> 3;
    const int bbase = (blockIdx.x & 7) * 16;
    const int tid = threadIdx.x;
    const int wid = tid >> 6, lane = tid & 63;
    const int col = lane & 15;
    const int kg = lane >> 4;

    for (int i = tid; i < WIN * 4; i += 128) {
        int t = i >> 2, q = i & 3;
        ((float4*)&zs[t][0])[q] = ((const float4*)&z[(size_t)t * (NFC1 * BATCH) + f * BATCH + bbase])[q];
    }
    // zero only slots read before first write: h0(-1) = slot RING-1; h1(-1) = parity 1
    for (int i = tid; i < 16 * LW; i += 128) {
        h0r_[RING - 1][i] = 0;
        h1p_[1][i] = 0;
    }
    if (tid < 2) flg[tid] = -1;

    const float gsc[4] = { -LOG2E, -LOG2E, LOG2E2, -LOG2E };
    bf16x8 fA[8], fB[8];
    float bias[8], wi0v[8];
    if (wid == 0) {
        const float* WA = w_hh + (size_t)f * 4096;            // layer0 hh
        #pragma unroll
        for (int nt = 0; nt < 8; ++nt) {
            int g = nt * 16 + col;
            float sc = gsc[nt >> 1];
            fA[nt] = load_row8_scaled(WA + g * 32 + kg * 8, sc);
            bias[nt] = b_lstm[f * 128 + g] * sc;
            wi0v[nt] = w_ih0[f * 128 + g] * sc;
        }
    } else {
        const float* WU = w_ih1 + (size_t)f * 4096;           // layer1 ih
        const float* WV = w_hh + (size_t)(NFC1 + f) * 4096;   // layer1 hh
        #pragma unroll
        for (int nt = 0; nt < 8; ++nt) {
            int g = nt * 16 + col;
            float sc = gsc[nt >> 1];
            fA[nt] = load_row8_scaled(WU + g * 32 + kg * 8, sc);
            fB[nt] = load_row8_scaled(WV + g * 32 + kg * 8, sc);
            bias[nt] = b_lstm[NFC1 * 128 + f * 128 + g] * sc;
        }
    }
    __syncthreads();   // init + weights visible (only block-wide barrier)

    const int hread = col * LW + kg * 8;
    volatile int* vflg = (volatile int*)flg;
    float cst[8] = {0.f, 0.f, 0.f, 0.f, 0.f, 0.f, 0.f, 0.f};

    if (wid == 0) {
        // ---------- layer0 producer ----------
        f32x4 zv = *(const f32x4*)&zs[0][kg * 4];
        int f1 = vflg[1];
        #pragma unroll 1
        for (int T = 0; T < WIN; T += GRP) {
            while (f1 < T - (RING - GRP + 1)) { f1 = vflg[1]; }   // ring slots free
            __builtin_amdgcn_sched_barrier(0);
            #pragma unroll
            for (int u = 0; u < GRP; ++u) {
                const int t = T + u;
                bf16x8 hA = *(const bf16x8*)&h0r_[(t + RING - 1) & (RING - 1)][hread]; // own h0(t-1)
                f32x4 acc[8];
                #pragma unroll
                for (int nt = 0; nt < 8; ++nt) {
                    #pragma unroll
                    for (int j = 0; j < 4; ++j)
                        acc[nt][j] = fmaf(zv[j], wi0v[nt], bias[nt]);
                }
                #pragma unroll
                for (int nt = 0; nt < 8; ++nt)
                    acc[nt] = __builtin_amdgcn_mfma_f32_16x16x32_bf16(hA, fA[nt], acc[nt], 0, 0, 0);
                if (t + 1 < WIN) zv = *(const f32x4*)&zs[t + 1][kg * 4];
                unsigned short* wb = &h0r_[t & (RING - 1)][0];
                #pragma unroll
                for (int sp = 0; sp < 2; ++sp) {
                    #pragma unroll
                    for (int j = 0; j < 4; ++j) {
                        float h = cellf(cst[sp * 4 + j], acc[sp][j], acc[2 + sp][j],
                                        acc[4 + sp][j], acc[6 + sp][j]);
                        wb[(kg * 4 + j) * LW + sp * 16 + col] = f2bf(h);
                    }
                }
            }
            asm volatile("s_waitcnt lgkmcnt(0)" ::: "memory");
            if (lane == 0) vflg[0] = T + GRP - 1;
            f1 = vflg[1];   // prefetch next group's backpressure flag
        }
    } else {
        // ---------- layer1 consumer ----------
        int f0 = vflg[0];
        #pragma unroll 1
        for (int T = 0; T < WIN; T += GRP) {
            while (f0 < T + GRP - 1) { f0 = vflg[0]; }            // h0(T..T+3) ready
            __builtin_amdgcn_sched_barrier(0);
            #pragma unroll
            for (int u = 0; u < GRP; ++u) {
                const int t = T + u;
                bf16x8 hA = *(const bf16x8*)&h0r_[t & (RING - 1)][hread];     // h0(t)
                bf16x8 hB = *(const bf16x8*)&h1p_[(t + 1) & 1][hread];        // own h1(t-1)
                f32x4 acc[8];
                #pragma unroll
                for (int nt = 0; nt < 8; ++nt) {
                    #pragma unroll
                    for (int j = 0; j < 4; ++j) acc[nt][j] = bias[nt];
                }
                #pragma unroll
                for (int nt = 0; nt < 8; ++nt) {
                    acc[nt] = __builtin_amdgcn_mfma_f32_16x16x32_bf16(hA, fA[nt], acc[nt], 0, 0, 0);
                    acc[nt] = __builtin_amdgcn_mfma_f32_16x16x32_bf16(hB, fB[nt], acc[nt], 0, 0, 0);
                }
                if (t < WIN - 1) {
                    unsigned short* wb = &h1p_[t & 1][0];
                    #pragma unroll
                    for (int sp = 0; sp < 2; ++sp) {
                        #pragma unroll
                        for (int j = 0; j < 4; ++j) {
                            float h = cellf(cst[sp * 4 + j], acc[sp][j], acc[2 + sp][j],
                                            acc[4 + sp][j], acc[6 + sp][j]);
                            wb[(kg * 4 + j) * LW + sp * 16 + col] = f2bf(h);
                        }
                    }
                } else {
                    #pragma unroll
                    for (int sp = 0; sp < 2; ++sp) {
                        #pragma unroll
                        for (int j = 0; j < 4; ++j) {
                            float h = cellf(cst[sp * 4 + j], acc[sp][j], acc[2 + sp][j],
                                            acc[4 + sp][j], acc[6 + sp][j]);
                            h1fin[(size_t)(bbase + kg * 4 + j) * (NFC1 * HS) + f * HS + sp * 16 + col] = h;
                        }
                    }
                }
            }
            asm volatile("s_waitcnt lgkmcnt(0)" ::: "memory");
            if (lane == 0) vflg[1] = T + GRP - 1;
            f0 = vflg[0];   // prefetch next group's readiness flag
        }
    }
}

// ---------------- K3: head (mu / logvar / CI bounds) ----------------
__global__ __launch_bounds__(128) void k3_head(
    const float* __restrict__ h1fin, const float* __restrict__ mu_w, const float* __restrict__ mu_b,
    const float* __restrict__ lv_w, const float* __restrict__ lv_b, float* __restrict__ out)
{
    const int b = blockIdx.x, tid = threadIdx.x;
    const float* hrow = h1fin + (size_t)b * (NFC1 * HS);
    float am = 0.f, al = 0.f;
    for (int i = tid; i < NFC1 * HS; i += 128) {
        float h = hrow[i];
        am = fmaf(h, mu_w[i], am);
        al = fmaf(h, lv_w[i], al);
    }
    for (int off = 32; off >= 1; off >>= 1) {
        am += __shfl_down(am, off, 64);
        al += __shfl_down(al, off, 64);
    }
    __shared__ float sm[2], sl[2];
    const int wv = tid >> 6, ln = tid & 63;
    if (ln == 0) { sm[wv] = am; sl[wv] = al; }
    __syncthreads();
    if (tid == 0) {
        float mu = sm[0] + sm[1] + mu_b[0];
        float lv = sl[0] + sl[1] + lv_b[0];
        float sg = expf(0.5f * lv);
        out[b]           = mu - 1.96f * sg;
        out[128 + b]     = mu;
        out[256 + b]     = mu + 1.96f * sg;
        out[384 + b]     = lv;
    }
}

extern "C" void kernel_launch(void* const* d_in, const int* in_sizes, int n_in,
                              void* d_out, int out_size, void* d_ws, size_t ws_size,
                              hipStream_t stream)
{
    const float* x      = (const float*)d_in[0];
    const float* conv_w = (const float*)d_in[1];
    const float* conv_b = (const float*)d_in[2];
    const float* fc1_w  = (const float*)d_in[3];
    const float* fc1_b  = (const float*)d_in[4];
    const float* w_ih0  = (const float*)d_in[5];
    const float* w_ih1  = (const float*)d_in[6];
    const float* w_hh   = (const float*)d_in[7];
    const float* b_lstm = (const float*)d_in[8];
    const float* mu_w   = (const float*)d_in[9];
    const float* mu_b   = (const float*)d_in[10];
    const float* lv_w   = (const float*)d_in[11];
    const float* lv_b   = (const float*)d_in[12];
    float* out = (float*)d_out;

    float* z     = (float*)d_ws;                              // 524288 floats
    float* h1fin = z + (size_t)WIN * NFC1 * BATCH;            // 131072 floats
    unsigned short* w_bf = (unsigned short*)(h1fin + (size_t)BATCH * NFC1 * HS);  // 32*KP bf16

    k0_wconv<<<dim3(NFC1), dim3(256), 0, stream>>>(fc1_w, w_bf);
    k1_conv_fc1<<<dim3(WIN * 8), dim3(256), 0, stream>>>(x, conv_w, conv_b, w_bf, fc1_b, z);
    k2_lstm_mfma<<<dim3(NFC1 * 8), dim3(128), 0, stream>>>(w_ih0, w_ih1, w_hh, b_lstm, z, h1fin);
    k3_head<<<dim3(BATCH), dim3(128), 0, stream>>>(h1fin, mu_w, mu_b, lv_w, lv_b, out);
}

// Round 16
// 83.146 us; speedup vs baseline: 1.4970x; 1.4970x over previous
//
#include <hip/hip_runtime.h>
#include <hip/hip_bf16.h>
#include <math.h>

#define BATCH 128
#define WIN   128      // time steps / conv groups
#define NF    128      // conv spatial length
#define KC    16
#define POOL  65
#define NFC1  32       // number of LSTMs
#define HS    32       // hidden size
#define LW    40       // k2 h-buffer row stride (bf16 elems, 80B)
#define KP    1056     // fc1 K padded to multiple of 32
#define PSTR  1064     // poolb row stride (bf16 elems; 2128B -> conflict-free b128 reads)

typedef float f32x4 __attribute__((ext_vector_type(4)));
typedef short bf16x8 __attribute__((ext_vector_type(8)));

#define LOG2E   1.442695041f
#define LOG2E2  2.885390082f

// gates arrive PRESCALED: i,f,o by -log2e ; g by +2*log2e (folded into weights).
// r6 form: sf = rcp(1+ef) keeps the recurrent c-chain short (c only waits on ef).
// 5 exp2 + 3 rcp + 1 med3; NaN-safe via c clamp.
__device__ __forceinline__ float cellf(float& c, float gi, float gf, float gg, float go) {
    float ei = __builtin_amdgcn_exp2f(gi);
    float ef = __builtin_amdgcn_exp2f(gf);
    float eg = __builtin_amdgcn_exp2f(gg);
    float eo = __builtin_amdgcn_exp2f(go);
    float sf = __builtin_amdgcn_rcpf(1.f + ef);
    c = fmaf(sf, c, (eg - 1.f) * __builtin_amdgcn_rcpf((1.f + ei) * (eg + 1.f)));
    float ec = __builtin_amdgcn_exp2f(__builtin_amdgcn_fmed3f(c, -30.f, 30.f) * LOG2E2);
    return (ec - 1.f) * __builtin_amdgcn_rcpf((1.f + eo) * (ec + 1.f));
}
__device__ __forceinline__ unsigned short f2bf(float x) {
    __hip_bfloat16 h = __float2bfloat16(x);
    unsigned short u; __builtin_memcpy(&u, &h, 2); return u;
}
__device__ __forceinline__ float bf2f(unsigned short u) {
    unsigned int v = ((unsigned int)u) << 16;
    float f; __builtin_memcpy(&f, &v, 4); return f;
}
__device__ __forceinline__ bf16x8 load_row8_scaled(const float* row, float sc) {
    float4 lo = ((const float4*)row)[0];
    float4 hi = ((const float4*)row)[1];
    union { bf16x8 v; unsigned short u[8]; } t;
    t.u[0] = f2bf(lo.x * sc); t.u[1] = f2bf(lo.y * sc); t.u[2] = f2bf(lo.z * sc); t.u[3] = f2bf(lo.w * sc);
    t.u[4] = f2bf(hi.x * sc); t.u[5] = f2bf(hi.y * sc); t.u[6] = f2bf(hi.z * sc); t.u[7] = f2bf(hi.w * sc);
    return t.v;
}

// ---------------- K0: convert fc1_w -> bf16, K-padded [32][KP] ----------------
__global__ __launch_bounds__(256) void k0_wconv(
    const float* __restrict__ fc1_w, unsigned short* __restrict__ w_bf)
{
    const int o = blockIdx.x;
    for (int i = threadIdx.x; i < KP; i += 256) {
        float v = (i < KC * POOL) ? fc1_w[(size_t)o * (KC * POOL) + i] : 0.f;
        w_bf[(size_t)o * KP + i] = f2bf(v);
    }
}

// ---------------- K1: grouped conv1d + relu + maxpool + fc1 (MFMA) ----------------
// grid = 128 w * 8 batch-tiles(16) = 1024 blocks of 256 threads (4 waves)
// -> 4 blocks/CU, 4 waves/SIMD (conv phase is latency-bound: more TLP).
__global__ __launch_bounds__(256, 4) void k1_conv_fc1(
    const float* __restrict__ x, const float* __restrict__ conv_w, const float* __restrict__ conv_b,
    const unsigned short* __restrict__ w_bf, const float* __restrict__ fc1_b, float* __restrict__ z)
{
    __shared__ __align__(16) unsigned short xp[16][132];     // bf16, xp[b][i] = x[i-1], 0-padded
    __shared__ __align__(16) unsigned short poolb[16 * PSTR];
    __shared__ float cw[KC][3];
    __shared__ float cb[KC];
    __shared__ float fb[NFC1];

    const int w = blockIdx.x >> 3;
    const int bbase = (blockIdx.x & 7) * 16;
    const int tid = threadIdx.x;

    if (tid < KC * 3) cw[tid / 3][tid % 3] = conv_w[(w * KC + tid / 3) * 3 + tid % 3];
    if (tid >= 64 && tid < 64 + KC) cb[tid - 64] = conv_b[w * KC + (tid - 64)];
    if (tid >= 96 && tid < 96 + NFC1) fb[tid - 96] = fc1_b[tid - 96];

    // vectorized x staging: 16 rows x 32 float4
    for (int i = tid; i < 16 * 32; i += 256) {
        int b = i >> 5, q = i & 31;
        float4 v = ((const float4*)(x + (size_t)(bbase + b) * (WIN * NF) + (size_t)w * NF))[q];
        unsigned short* dst = &xp[b][1 + q * 4];
        dst[0] = f2bf(v.x); dst[1] = f2bf(v.y); dst[2] = f2bf(v.z); dst[3] = f2bf(v.w);
    }
    if (tid < 16) { xp[tid][0] = 0; xp[tid][129] = 0; xp[tid][130] = 0; xp[tid][131] = 0; }
    __syncthreads();

    // conv + relu + pool: thread -> (b = tid>>4, k = tid&15); sliding window over xp
    {
        const int b = tid >> 4;        // 0..15
        const int k = tid & 15;
        const float w0 = cw[k][0], w1 = cw[k][1], w2 = cw[k][2], bb = cb[k];
        float v1 = 0.f;
        float v2 = bf2f(xp[b][0]);
        float v3 = bf2f(xp[b][1]);
        unsigned short* prow = &poolb[b * PSTR + k * POOL];
        #pragma unroll 5
        for (int j = 0; j < POOL; ++j) {
            float v0 = v1; v1 = v2; v2 = v3;
            v3 = bf2f(xp[b][2 * j + 2]);
            float oa = bb + w0 * v0 + w1 * v1 + w2 * v2;   // out(2j-1)
            float ob = bb + w0 * v1 + w1 * v2 + w2 * v3;   // out(2j)
            float m = 0.f;                                  // relu floor
            if (j > 0)        m = fmaxf(m, oa);
            if (j < POOL - 1) m = fmaxf(m, ob);
            prow[j] = f2bf(m);
        }
    }
    // zero K-pad tail (cols 1040..1055)
    for (int i = tid; i < 16 * (KP - KC * POOL); i += 256) {
        int b = i >> 4, c = i & 15;
        poolb[b * PSTR + KC * POOL + c] = 0;
    }
    __syncthreads();

    // fc1 MFMA: waves 0,1 -> o-tiles; waves 2,3 idle (phase is short)
    const int lane = tid & 63;
    const int wid = tid >> 6;
    if (wid < 2) {
        const int col = lane & 15;
        const int kg = lane >> 4;
        const int g = wid * 16 + col;
        f32x4 acc;
        {
            float bias = fb[g];
            acc[0] = bias; acc[1] = bias; acc[2] = bias; acc[3] = bias;
        }
        const unsigned short* wrow = w_bf + (size_t)g * KP;
        #pragma unroll 4
        for (int ks = 0; ks < KP / 32; ++ks) {
            bf16x8 aP = *(const bf16x8*)&poolb[col * PSTR + ks * 32 + kg * 8];
            bf16x8 bW = *(const bf16x8*)&wrow[ks * 32 + kg * 8];
            acc = __builtin_amdgcn_mfma_f32_16x16x32_bf16(aP, bW, acc, 0, 0, 0);
        }
        float4 st; st.x = acc[0]; st.y = acc[1]; st.z = acc[2]; st.w = acc[3];
        *(float4*)&z[(size_t)w * (NFC1 * BATCH) + (size_t)g * BATCH + bbase + kg * 4] = st;
    }
}

// ---------------- K2: 2-layer LSTM via bf16 MFMA (r11 structure) + fused head partials --
// grid = 32 f * 8 batch-tiles(16) = 256 blocks of 256 threads (4 waves) -> 1 block/CU.
// waves 0,1 = layer0 (s halves); waves 2,3 = layer1 one step behind.
// Static parity double-buffer, 2x-unrolled loop, 1 barrier/step.
// At the final step, L1 waves fold h1(T) into mu/lv partials in-register
// (16-lane shfl tree) and store per-(f,s,batch) partials (64x smaller than h1fin).
__global__ __launch_bounds__(256, 1) void k2_lstm_mfma(
    const float* __restrict__ w_ih0, const float* __restrict__ w_ih1,
    const float* __restrict__ w_hh, const float* __restrict__ b_lstm,
    const float* __restrict__ mu_w, const float* __restrict__ lv_w,
    const float* __restrict__ z, float* __restrict__ pm, float* __restrict__ pl)
{
    __shared__ float zs[WIN][16];
    __shared__ __align__(16) unsigned short h0b0[16 * LW];
    __shared__ __align__(16) unsigned short h0b1[16 * LW];
    __shared__ __align__(16) unsigned short h1b0[16 * LW];
    __shared__ __align__(16) unsigned short h1b1[16 * LW];

    const int f = blockIdx.x >> 3;
    const int bbase = (blockIdx.x & 7) * 16;
    const int tid = threadIdx.x;
    const int wid = tid >> 6, lane = tid & 63;
    const bool isL0 = (wid < 2);
    const int s = wid & 1;
    const int col = lane & 15;
    const int kg = lane >> 4;

    // vectorized z staging: zs[t][0..15] = z[t][f][bbase..bbase+15]
    for (int i = tid; i < WIN * 4; i += 256) {
        int t = i >> 2, q = i & 3;
        ((float4*)&zs[t][0])[q] = ((const float4*)&z[(size_t)t * (NFC1 * BATCH) + f * BATCH + bbase])[q];
    }
    for (int i = tid; i < 16 * LW; i += 256) {
        h0b0[i] = 0; h0b1[i] = 0; h1b0[i] = 0; h1b1[i] = 0;
    }

    // gate-type scale factors (exp2 domain)
    const float gsc[4] = { -LOG2E, -LOG2E, LOG2E2, -LOG2E };

    const float* WA = isL0 ? (w_hh + (size_t)f * 4096)
                           : (w_ih1 + (size_t)f * 4096);
    const float* WV = w_hh + (size_t)(NFC1 + f) * 4096;
    bf16x8 fA[4], fB[4];
    float bias[4], wi0[4];
    float mw = 0.f, lw = 0.f;
    const int loff = isL0 ? 0 : (NFC1 * 128);
    #pragma unroll
    for (int gi = 0; gi < 4; ++gi) {
        int nt = gi * 2 + s;
        int g = nt * 16 + col;
        fA[gi] = load_row8_scaled(WA + g * 32 + kg * 8, gsc[gi]);
        if (!isL0) fB[gi] = load_row8_scaled(WV + g * 32 + kg * 8, gsc[gi]);
        bias[gi] = b_lstm[loff + f * 128 + g] * gsc[gi];
        wi0[gi] = w_ih0[f * 128 + g] * gsc[gi];
    }
    if (!isL0) {
        mw = mu_w[f * HS + 16 * s + col];
        lw = lv_w[f * HS + 16 * s + col];
    }
    __syncthreads();

    const int hread = col * LW + kg * 8;
    const int hw0 = (kg * 4 + 0) * LW + 16 * s + col;
    float cst[4] = {0.f, 0.f, 0.f, 0.f};
    f32x4 zv = *(const f32x4*)&zs[0][kg * 4];

    auto body = [&](int it, const unsigned short* h0r, unsigned short* h0w,
                            const unsigned short* h1r, unsigned short* h1w) {
        if (isL0) {
            if (it < WIN) {
                bf16x8 hA = *(const bf16x8*)&h0r[hread];
                f32x4 aI, aF, aG, aO;
                #pragma unroll
                for (int j = 0; j < 4; ++j) {
                    aI[j] = fmaf(zv[j], wi0[0], bias[0]);
                    aF[j] = fmaf(zv[j], wi0[1], bias[1]);
                    aG[j] = fmaf(zv[j], wi0[2], bias[2]);
                    aO[j] = fmaf(zv[j], wi0[3], bias[3]);
                }
                aI = __builtin_amdgcn_mfma_f32_16x16x32_bf16(hA, fA[0], aI, 0, 0, 0);
                aF = __builtin_amdgcn_mfma_f32_16x16x32_bf16(hA, fA[1], aF, 0, 0, 0);
                aG = __builtin_amdgcn_mfma_f32_16x16x32_bf16(hA, fA[2], aG, 0, 0, 0);
                aO = __builtin_amdgcn_mfma_f32_16x16x32_bf16(hA, fA[3], aO, 0, 0, 0);
                if (it + 1 < WIN) zv = *(const f32x4*)&zs[it + 1][kg * 4];
                #pragma unroll
                for (int j = 0; j < 4; ++j) {
                    float h = cellf(cst[j], aI[j], aF[j], aG[j], aO[j]);
                    h0w[hw0 + j * LW] = f2bf(h);
                }
            }
        } else {
            if (it >= 1) {
                bf16x8 hA = *(const bf16x8*)&h0r[hread];
                bf16x8 hB = *(const bf16x8*)&h1r[hread];
                f32x4 aI, aF, aG, aO;
                #pragma unroll
                for (int j = 0; j < 4; ++j) { aI[j] = bias[0]; aF[j] = bias[1]; aG[j] = bias[2]; aO[j] = bias[3]; }
                aI = __builtin_amdgcn_mfma_f32_16x16x32_bf16(hA, fA[0], aI, 0, 0, 0);
                aI = __builtin_amdgcn_mfma_f32_16x16x32_bf16(hB, fB[0], aI, 0, 0, 0);
                aF = __builtin_amdgcn_mfma_f32_16x16x32_bf16(hA, fA[1], aF, 0, 0, 0);
                aF = __builtin_amdgcn_mfma_f32_16x16x32_bf16(hB, fB[1], aF, 0, 0, 0);
                aG = __builtin_amdgcn_mfma_f32_16x16x32_bf16(hA, fA[2], aG, 0, 0, 0);
                aG = __builtin_amdgcn_mfma_f32_16x16x32_bf16(hB, fB[2], aG, 0, 0, 0);
                aO = __builtin_amdgcn_mfma_f32_16x16x32_bf16(hA, fA[3], aO, 0, 0, 0);
                aO = __builtin_amdgcn_mfma_f32_16x16x32_bf16(hB, fB[3], aO, 0, 0, 0);
                if (it < WIN) {
                    #pragma unroll
                    for (int j = 0; j < 4; ++j) {
                        float h = cellf(cst[j], aI[j], aF[j], aG[j], aO[j]);
                        h1w[hw0 + j * LW] = f2bf(h);
                    }
                } else {
                    // final step: fuse head partials (mu/lv dot over this wave's 16 elems)
                    f32x4 pmv, plv;
                    #pragma unroll
                    for (int j = 0; j < 4; ++j) {
                        float h = cellf(cst[j], aI[j], aF[j], aG[j], aO[j]);
                        pmv[j] = h * mw;
                        plv[j] = h * lw;
                    }
                    #pragma unroll
                    for (int m = 1; m < 16; m <<= 1) {
                        #pragma unroll
                        for (int j = 0; j < 4; ++j) {
                            pmv[j] += __shfl_xor(pmv[j], m, 64);
                            plv[j] += __shfl_xor(plv[j], m, 64);
                        }
                    }
                    if (col == 0) {
                        #pragma unroll
                        for (int j = 0; j < 4; ++j) {
                            pm[(size_t)(f * 2 + s) * BATCH + bbase + kg * 4 + j] = pmv[j];
                            pl[(size_t)(f * 2 + s) * BATCH + bbase + kg * 4 + j] = plv[j];
                        }
                    }
                }
            }
        }
    };

    body(0, h0b0, h0b1, h1b0, h1b1);
    __syncthreads();
    #pragma unroll 1
    for (int it = 1; it <= WIN; it += 2) {
        body(it,     h0b1, h0b0, h1b1, h1b0);
        __syncthreads();
        body(it + 1, h0b0, h0b1, h1b0, h1b1);
        __syncthreads();
    }
}

// ---------------- K3: tiny head finisher (sum 64 partials per batch) ----------------
__global__ __launch_bounds__(128) void k3_head(
    const float* __restrict__ pm, const float* __restrict__ pl,
    const float* __restrict__ mu_b, const float* __restrict__ lv_b, float* __restrict__ out)
{
    const int b = threadIdx.x;
    float am = mu_b[0], al = lv_b[0];
    #pragma unroll 8
    for (int i = 0; i < 2 * NFC1; ++i) {
        am += pm[i * BATCH + b];
        al += pl[i * BATCH + b];
    }
    float sg = __expf(0.5f * al);
    out[b]           = am - 1.96f * sg;
    out[128 + b]     = am;
    out[256 + b]     = am + 1.96f * sg;
    out[384 + b]     = al;
}

extern "C" void kernel_launch(void* const* d_in, const int* in_sizes, int n_in,
                              void* d_out, int out_size, void* d_ws, size_t ws_size,
                              hipStream_t stream)
{
    const float* x      = (const float*)d_in[0];
    const float* conv_w = (const float*)d_in[1];
    const float* conv_b = (const float*)d_in[2];
    const float* fc1_w  = (const float*)d_in[3];
    const float* fc1_b  = (const float*)d_in[4];
    const float* w_ih0  = (const float*)d_in[5];
    const float* w_ih1  = (const float*)d_in[6];
    const float* w_hh   = (const float*)d_in[7];
    const float* b_lstm = (const float*)d_in[8];
    const float* mu_w   = (const float*)d_in[9];
    const float* mu_b   = (const float*)d_in[10];
    const float* lv_w   = (const float*)d_in[11];
    const float* lv_b   = (const float*)d_in[12];
    float* out = (float*)d_out;

    float* z  = (float*)d_ws;                                 // 524288 floats
    float* pm = z + (size_t)WIN * NFC1 * BATCH;               // 2*NFC1*BATCH = 8192 floats
    float* pl = pm + (size_t)2 * NFC1 * BATCH;                // 8192 floats
    unsigned short* w_bf = (unsigned short*)(z + 524288 + 131072);  // 32*KP bf16 (past old h1fin area)

    k0_wconv<<<dim3(NFC1), dim3(256), 0, stream>>>(fc1_w, w_bf);
    k1_conv_fc1<<<dim3(WIN * 8), dim3(256), 0, stream>>>(x, conv_w, conv_b, w_bf, fc1_b, z);
    k2_lstm_mfma<<<dim3(NFC1 * 8), dim3(256), 0, stream>>>(w_ih0, w_ih1, w_hh, b_lstm,
                                                           mu_w, lv_w, z, pm, pl);
    k3_head<<<dim3(1), dim3(128), 0, stream>>>(pm, pl, mu_b, lv_b, out);
}